// Round 6
// baseline (6000464.844 us; speedup 1.0000x reference)
//
#include <hip/hip_runtime.h>

// Problem: B=256, N=1000, D=128, H=8, dk=16.
// R7b (3rd submit; 2x "container failed twice" = presumed infra): identical to
// R7 except the pair spin-wait is BOUNDED (~2s via s_memrealtime). If the sync
// ever fails to pair up, the kernel exits with wrong results (bench reports
// passed:false) instead of hanging the GPU/container -> disambiguates
// kernel-hang vs infra on the next failure.
//
// R7 changes vs R6 (Occ 90% proven, but 563us due to two poisons):
//  (1) __launch_bounds__(1024,8) budgeted 32 VGPRs -> ~1.5GB scratch spill
//      (WRITE_SIZE 744MB, VALUBusy 6.6%). Now plain __launch_bounds__(1024).
//  (2) __threadfence() acquire invalidated L1+L2 each pair sync -> E refetch.
//      Now partner ws data read via agent-scope RELAXED atomic loads only.
// Fallback: coop-launch rejection -> verified R0 single-block kernel.

#define NEG (-1e9f)

__device__ __forceinline__ float ld_agent(const float* p) {
    return __hip_atomic_load((float*)p, __ATOMIC_RELAXED, __HIP_MEMORY_SCOPE_AGENT);
}

__device__ __forceinline__ void pair_arrive_wait(int* c, int target) {
    __syncthreads();                      // all waves' global stores drained (vmcnt 0)
    if (threadIdx.x == 0) {
        // release RMW: wbL2 before the atomic -> our half's ws data at the
        // device coherence point before the counter bump becomes visible
        __hip_atomic_fetch_add(c, 1, __ATOMIC_RELEASE, __HIP_MEMORY_SCOPE_AGENT);
        const long long t0 = (long long)__builtin_amdgcn_s_memrealtime();
        while (__hip_atomic_load(c, __ATOMIC_RELAXED, __HIP_MEMORY_SCOPE_AGENT) < target) {
            __builtin_amdgcn_s_sleep(4);
            // ~100 MHz realtime clock: 2e8 ticks ~= 2 s. Bail instead of hang.
            if ((long long)__builtin_amdgcn_s_memrealtime() - t0 > 200000000LL) break;
        }
    }
    __syncthreads();
    // NOTE: no threadfence. Partner data must be read with ld_agent() only.
}

__global__ __launch_bounds__(1024) void k_pair(
    const float* __restrict__ E, const float* __restrict__ Wn,
    const float* __restrict__ Wf, const float* __restrict__ Ws,
    const float* __restrict__ Wo,
    const int* __restrict__ fi, const int* __restrict__ li,
    const int* __restrict__ maskI, const unsigned char* __restrict__ maskB,
    float* __restrict__ out, float* __restrict__ ws)
{
    const int bid  = blockIdx.x;
    const int b    = bid & 255;
    const int half = bid >> 8;
    const int blk  = b * 2 + half;
    const int i0   = b * 2, i1 = b * 2 + 1;
    const int t    = threadIdx.x;
    const int r0g  = half * 500;          // first global row of this half

    int*   cnt  = (int*)ws;               // [256]  (memset to 0 each launch)
    float* muP  = ws + 256;               // [512][128] partial sums
    float* wsU  = muP + 512 * 128;        // [512][8*128] unnormalized Ebar numerator
    float* wsML = wsU + (size_t)512 * 1024; // [512][16] = m[8], l[8]
    float* wsZ  = wsML + 512 * 16;        // [512][2]  = zmax, zsum

    __shared__ float4 Et4[2048];     // 32 KB: mean scratch / 64-row E tile / slice reduce
    __shared__ float4 qk4[256];      // qkp, float4-slot swizzle s^(s>>2)
    __shared__ float4 pt4[128];      // p [row][h] in phase C; z[] (500) in phase E
    __shared__ float4 EbarF4[256];
    __shared__ float4 mu4[32], e14[32], e24[32], gp4[32];
    __shared__ float q[128], heads[128], gl[128];
    __shared__ float qred[8][128];
    __shared__ float ct[128 * 9];    // compat [row][h] pad 9 (64 rows in C; 128 in E)
    __shared__ float redh[72];
    __shared__ float mh[8], lh[8], al[8];
    __shared__ float red[16];
    __shared__ float stat[2];
    __shared__ int flagS;

    float* const mu    = (float*)mu4;
    float* const e1    = (float*)e14;
    float* const e2    = (float*)e24;
    float* const gp    = (float*)gp4;
    float* const pt    = (float*)pt4;
    float* const EbarF = (float*)EbarF4;
    float* const qkf   = (float*)qk4;
    float* const Etf   = (float*)Et4;

    const float4* E4 = (const float4*)(E + (size_t)b * 128000);

    if (t == 0) flagS = 0;
    // mask-format probe: int32 upload => upper 3 bytes of every word zero.
    const uint4 dv = ((const uint4*)maskI)[t];           // first 16 KB
    const unsigned det = (dv.x | dv.y | dv.z | dv.w) & 0xFFFFFF00u;

    // ---- Phase A: partial graph mean over this half's 500 rows ----
    {
        const int cm = t & 31, sm = t >> 5;
        float4 acc = make_float4(0.f, 0.f, 0.f, 0.f);
        for (int r = sm; r < 500; r += 32) {
            const float4 v = E4[(r0g + r) * 32 + cm];
            acc.x += v.x; acc.y += v.y; acc.z += v.z; acc.w += v.w;
        }
        Et4[t] = acc;
    }
    if (t >= 512 && t < 544) {
        e14[t - 512] = E4[fi[b] * 32 + (t - 512)];
    } else if (t >= 544 && t < 576) {
        e24[t - 544] = E4[li[b] * 32 + (t - 544)];
    }
    __syncthreads();
    if (det) atomicOr(&flagS, 1);
    if (t < 32) {
        float4 acc = Et4[t];
        #pragma unroll
        for (int s = 1; s < 32; ++s) {
            const float4 v = Et4[s * 32 + t];
            acc.x += v.x; acc.y += v.y; acc.z += v.z; acc.w += v.w;
        }
        ((float4*)(muP + (size_t)blk * 128))[t] = acc;   // partial SUM (not mean)
    }
    pair_arrive_wait(&cnt[b], 2);
    if (t < 128) {
        const float p0 = ld_agent(&muP[(size_t)i0 * 128 + t]);
        const float p1 = ld_agent(&muP[(size_t)i1 * 128 + t]);
        mu[t] = (p0 + p1) * (1.0f / 1000.0f);
    }
    __syncthreads();

    // ---- Phase B: q = mu@Wf + e1@Ws[0:128] + e2@Ws[128:256], 8-way k-split ----
    {
        const int part = t >> 7, d = t & 127;
        float acc = 0.f;
        const int k0 = part * 48;
        for (int k = k0; k < k0 + 48; ++k) {
            const float s = (k < 128) ? mu[k] : (k < 256 ? e1[k - 128] : e2[k - 256]);
            const float w = (k < 128) ? Wf[k * 128 + d] : Ws[(k - 128) * 128 + d];
            acc += s * w;
        }
        qred[part][d] = acc;
    }
    __syncthreads();
    if (t < 128) {
        float acc = 0.f;
        #pragma unroll
        for (int p = 0; p < 8; ++p) acc += qred[p][t];
        q[t] = acc;
    }
    __syncthreads();
    // qkp[h][c] -> qk4 (LDS only)
    {
        const int j = t & 127, cg = t >> 7;
        const float qj = q[j];
        for (int c0 = 0; c0 < 128; c0 += 8) {
            const int c = c0 + cg;
            float v = Wn[c * 384 + j] * qj;
            v += __shfl_down(v, 8, 16);
            v += __shfl_down(v, 4, 16);
            v += __shfl_down(v, 2, 16);
            v += __shfl_down(v, 1, 16);
            if ((j & 15) == 0) {
                const int h = j >> 4, s = c >> 2;
                qkf[h * 128 + (s ^ (s >> 2)) * 4 + (c & 3)] = v * 0.25f;
            }
        }
    }
    __syncthreads();

    const bool useB = (flagS != 0);

    // ---- Phase C: online-softmax glimpse attention, 8 tiles x 64 rows ----
    if (t < 8) { mh[t] = -3e38f; lh[t] = 0.f; }
    float eacc[8];
    #pragma unroll
    for (int h = 0; h < 8; ++h) eacc[h] = 0.f;
    const int rr = t >> 4, qq = t & 15;    // stage: 64 rows x 16 lanes
    const int esl = t >> 7, ec = t & 127;  // Ebar: 8 slices x 128 cols
    const int g1 = qq, g2 = qq + 16;
    const int sg1 = g1 ^ (g1 >> 2), sg2 = g2 ^ (g2 >> 2);

    for (int tile = 0; tile < 8; ++tile) {
        const int lr = tile * 64 + rr;
        const bool valid = (lr < 500);
        {
            float4 v0 = make_float4(0.f, 0.f, 0.f, 0.f), v1 = v0;
            if (valid) {
                v0 = E4[(r0g + lr) * 32 + g1];
                v1 = E4[(r0g + lr) * 32 + g2];
            }
            bool msk = !valid;
            if (valid && qq < 8)
                msk = useB ? (maskB[b * 1000 + r0g + lr] != 0)
                           : (maskI[b * 1000 + r0g + lr] != 0);
            Et4[rr * 32 + g1] = v0;        // linear row-major tile
            Et4[rr * 32 + g2] = v1;
            float pch[8];
            #pragma unroll
            for (int h = 0; h < 8; ++h) {
                const float4 w0 = qk4[h * 32 + sg1];
                const float4 w1 = qk4[h * 32 + sg2];
                pch[h] = v0.x * w0.x + v0.y * w0.y + v0.z * w0.z + v0.w * w0.w
                       + v1.x * w1.x + v1.y * w1.y + v1.z * w1.z + v1.w * w1.w;
            }
            #pragma unroll
            for (int m = 1; m <= 8; m <<= 1) {
                #pragma unroll
                for (int h = 0; h < 8; ++h) pch[h] += __shfl_xor(pch[h], m, 16);
            }
            if (qq < 8) ct[rr * 9 + qq] = msk ? NEG : pch[qq];
        }
        __syncthreads();
        if (t < 64) {
            const int h = t & 7, part = t >> 3;
            float mt = -3e38f;
            const int rb = part * 8;
            #pragma unroll
            for (int r = 0; r < 8; ++r) mt = fmaxf(mt, ct[(rb + r) * 9 + h]);
            redh[part * 9 + h] = mt;
        }
        __syncthreads();
        if (t < 8) {
            float mt = redh[t];
            #pragma unroll
            for (int p = 1; p < 8; ++p) mt = fmaxf(mt, redh[p * 9 + t]);
            const float mnew = fmaxf(mh[t], mt);
            al[t] = __expf(mh[t] - mnew);
            mh[t] = mnew;
        }
        __syncthreads();
        if (t < 512) {
            const int row = t >> 3, h = t & 7;
            pt[row * 8 + h] = __expf(ct[row * 9 + h] - mh[h]);
        }
        __syncthreads();
        {
            #pragma unroll
            for (int h = 0; h < 8; ++h) eacc[h] *= al[h];
            #pragma unroll
            for (int j = 0; j < 8; ++j) {
                const int r = esl * 8 + j;
                const float ev = Etf[r * 128 + ec];    // stride-1 across lanes: 2-way, free
                const float4 p0 = pt4[r * 2];          // broadcast
                const float4 p1 = pt4[r * 2 + 1];
                eacc[0] += p0.x * ev; eacc[1] += p0.y * ev;
                eacc[2] += p0.z * ev; eacc[3] += p0.w * ev;
                eacc[4] += p1.x * ev; eacc[5] += p1.y * ev;
                eacc[6] += p1.z * ev; eacc[7] += p1.w * ev;
            }
        }
        if (t < 64) {
            const int h = t & 7, part = t >> 3;
            float s = 0.f;
            const int rb = part * 8;
            #pragma unroll
            for (int r = 0; r < 8; ++r) s += pt[(rb + r) * 8 + h];
            redh[part * 9 + h] = s;
        }
        __syncthreads();
        // post-barrier lh update: redh/al not overwritten until next tile's
        // writers pass their next barrier — safe.
        if (t < 8) {
            float s = 0.f;
            #pragma unroll
            for (int p = 0; p < 8; ++p) s += redh[p * 9 + t];
            lh[t] = lh[t] * al[t] + s;
        }
    }

    // ---- slice reduce (8 slices fit Et in one go), publish {U,m,l} ----
    #pragma unroll
    for (int h = 0; h < 8; ++h) Etf[esl * 1024 + h * 128 + ec] = eacc[h];
    __syncthreads();
    {
        float s = 0.f;
        #pragma unroll
        for (int s2 = 0; s2 < 8; ++s2) s += Etf[s2 * 1024 + t];
        wsU[(size_t)blk * 1024 + t] = s;           // unnormalized, local max
    }
    if (t < 8) wsML[blk * 16 + t] = mh[t];
    else if (t < 16) wsML[blk * 16 + t] = lh[t - 8];
    pair_arrive_wait(&cnt[b], 4);
    // combine halves: Ebar = (U0*w0 + U1*w1) / (l0*w0 + l1*w1), w_i = exp(m_i - M)
    if (t < 8) {
        const float m0 = ld_agent(&wsML[i0 * 16 + t]);
        const float m1 = ld_agent(&wsML[i1 * 16 + t]);
        const float l0 = ld_agent(&wsML[i0 * 16 + 8 + t]);
        const float l1 = ld_agent(&wsML[i1 * 16 + 8 + t]);
        const float M = fmaxf(m0, m1);
        const float w0 = __expf(m0 - M), w1 = __expf(m1 - M);
        const float L = l0 * w0 + l1 * w1;
        redh[t] = w0 / L;
        redh[8 + t] = w1 / L;
    }
    __syncthreads();
    {
        const int h = t >> 7;
        const float u0 = ld_agent(&wsU[(size_t)i0 * 1024 + t]);
        const float u1 = ld_agent(&wsU[(size_t)i1 * 1024 + t]);
        EbarF[t] = u0 * redh[h] + u1 * redh[8 + h];
    }
    __syncthreads();

    // ---- Phase D: heads -> glimpse -> gp, 8-way k-split each (duplicated) ----
    {
        const int part = t >> 7, d = t & 127, h = d >> 4;
        float acc = 0.f;
        const int c0 = part * 16;
        for (int c = c0; c < c0 + 16; ++c) acc += EbarF[h * 128 + c] * Wn[c * 384 + 128 + d];
        qred[part][d] = acc;
    }
    __syncthreads();
    if (t < 128) {
        float acc = 0.f;
        #pragma unroll
        for (int p = 0; p < 8; ++p) acc += qred[p][t];
        heads[t] = acc;
    }
    __syncthreads();
    {
        const int part = t >> 7, d = t & 127;
        float acc = 0.f;
        const int j0 = part * 16;
        for (int j = j0; j < j0 + 16; ++j) acc += heads[j] * Wo[j * 128 + d];
        qred[part][d] = acc;
    }
    __syncthreads();
    if (t < 128) {
        float acc = 0.f;
        #pragma unroll
        for (int p = 0; p < 8; ++p) acc += qred[p][t];
        gl[t] = acc;
    }
    __syncthreads();
    {
        const int part = t >> 7, c = t & 127;
        float acc = 0.f;
        const int d0 = part * 16;
        for (int d = d0; d < d0 + 16; ++d) acc += Wn[c * 384 + 256 + d] * gl[d];
        qred[part][c] = acc;
    }
    __syncthreads();
    if (t < 128) {
        float acc = 0.f;
        #pragma unroll
        for (int p = 0; p < 8; ++p) acc += qred[p][t];
        gp[t] = acc * 0.08838834764831845f;   // 1/sqrt(128)
    }
    __syncthreads();

    // ---- Phase E: logits for this half's 500 rows + split log_softmax ----
    {
        const int row = t >> 3, sub = t & 7;
        for (int tile = 0; tile < 4; ++tile) {
            const int lr = tile * 128 + row;
            float acc = 0.f;
            if (lr < 500) {
                const int g = r0g + lr;
                #pragma unroll
                for (int i = 0; i < 4; ++i) {
                    const float4 v = E4[g * 32 + sub * 4 + i];
                    const float4 w = gp4[sub * 4 + i];
                    acc += v.x * w.x + v.y * w.y + v.z * w.z + v.w * w.w;
                }
            }
            ct[row * 9 + sub] = acc;
            __syncthreads();
            if (t < 128) {
                const int lr2 = tile * 128 + t;
                if (lr2 < 500) {
                    float s = 0.f;
                    #pragma unroll
                    for (int k = 0; k < 8; ++k) s += ct[t * 9 + k];
                    float zz = 10.0f * tanhf(s);
                    const int g2 = r0g + lr2;
                    const bool m = useB ? (maskB[b * 1000 + g2] != 0)
                                        : (maskI[b * 1000 + g2] != 0);
                    if (m) zz = NEG;
                    pt[lr2] = zz;
                }
            }
            __syncthreads();
        }
    }
    // local max/sum over 500, then pair-combine LSE
    {
        float v = (t < 500) ? pt[t] : -3e38f;
        if (t < 512) {
            #pragma unroll
            for (int off = 32; off > 0; off >>= 1) v = fmaxf(v, __shfl_down(v, off, 64));
            if ((t & 63) == 0) red[t >> 6] = v;
        }
    }
    __syncthreads();
    if (t == 0) {
        float m = red[0];
        for (int i = 1; i < 8; ++i) m = fmaxf(m, red[i]);
        stat[0] = m;
    }
    __syncthreads();
    {
        float sv = (t < 500) ? __expf(pt[t] - stat[0]) : 0.f;
        if (t < 512) {
            #pragma unroll
            for (int off = 32; off > 0; off >>= 1) sv += __shfl_down(sv, off, 64);
            if ((t & 63) == 0) red[t >> 6] = sv;
        }
    }
    __syncthreads();
    if (t == 0) {
        float s = 0.f;
        for (int i = 0; i < 8; ++i) s += red[i];
        wsZ[blk * 2] = stat[0];
        wsZ[blk * 2 + 1] = s;
    }
    pair_arrive_wait(&cnt[b], 6);
    if (t == 0) {
        const float m0 = ld_agent(&wsZ[i0 * 2]), s0 = ld_agent(&wsZ[i0 * 2 + 1]);
        const float m1 = ld_agent(&wsZ[i1 * 2]), s1 = ld_agent(&wsZ[i1 * 2 + 1]);
        const float M = fmaxf(m0, m1);
        const float S = s0 * __expf(m0 - M) + s1 * __expf(m1 - M);
        stat[1] = M + __logf(S);
    }
    __syncthreads();
    if (t < 500)
        out[(size_t)b * 1000 + r0g + t] = pt[t] - stat[1];
}

// ======================= fallback: verified R0 single-block kernel ==========
__global__ __launch_bounds__(1024) void k_fused1(
    const float* __restrict__ E, const float* __restrict__ Wn,
    const float* __restrict__ Wf, const float* __restrict__ Ws,
    const float* __restrict__ Wo,
    const int* __restrict__ fi, const int* __restrict__ li,
    const int* __restrict__ maskI, const unsigned char* __restrict__ maskB,
    float* __restrict__ out)
{
    const int b = blockIdx.x;
    const int t = threadIdx.x;

    __shared__ float4 Et[4096];
    __shared__ float4 qk4[256];
    __shared__ float4 pt4[256];
    __shared__ float4 EbarF4[256];
    __shared__ float4 mu4[32], e14[32], e24[32], gp4[32];
    __shared__ float q[128], heads[128], gl[128];
    __shared__ float qred[8][128];
    __shared__ float ct[128 * 9];
    __shared__ float redh[72];
    __shared__ float mh[8], lh[8], al[8];
    __shared__ float red[16];
    __shared__ float stat[2];
    __shared__ int flagS;

    float* const mu = (float*)mu4;
    float* const e1 = (float*)e14;
    float* const e2 = (float*)e24;
    float* const gp = (float*)gp4;
    float* const pt = (float*)pt4;
    float* const EbarF = (float*)EbarF4;
    float* const qkf = (float*)qk4;

    const float4* E4 = (const float4*)(E + (size_t)b * 128000);

    if (t == 0) flagS = 0;
    const uint4 dv = ((const uint4*)maskI)[t];
    const unsigned det = (dv.x | dv.y | dv.z | dv.w) & 0xFFFFFF00u;

    {
        const int cm = t & 31, sm = t >> 5;
        float4 acc = make_float4(0.f, 0.f, 0.f, 0.f);
        for (int r = sm; r < 1000; r += 32) {
            const float4 v = E4[r * 32 + cm];
            acc.x += v.x; acc.y += v.y; acc.z += v.z; acc.w += v.w;
        }
        Et[t] = acc;
    }
    if (t >= 512 && t < 544) {
        e14[t - 512] = E4[fi[b] * 32 + (t - 512)];
    } else if (t >= 544 && t < 576) {
        e24[t - 544] = E4[li[b] * 32 + (t - 544)];
    }
    __syncthreads();
    if (det) atomicOr(&flagS, 1);
    if (t < 32) {
        float4 acc = Et[t];
        #pragma unroll
        for (int s = 1; s < 32; ++s) {
            const float4 v = Et[s * 32 + t];
            acc.x += v.x; acc.y += v.y; acc.z += v.z; acc.w += v.w;
        }
        const float inv = 1.0f / 1000.0f;
        mu4[t] = make_float4(acc.x * inv, acc.y * inv, acc.z * inv, acc.w * inv);
    }
    __syncthreads();

    {
        const int part = t >> 7, d = t & 127;
        float acc = 0.f;
        const int k0 = part * 48;
        for (int k = k0; k < k0 + 48; ++k) {
            const float s = (k < 128) ? mu[k] : (k < 256 ? e1[k - 128] : e2[k - 256]);
            const float w = (k < 128) ? Wf[k * 128 + d] : Ws[(k - 128) * 128 + d];
            acc += s * w;
        }
        qred[part][d] = acc;
    }
    __syncthreads();
    if (t < 128) {
        float acc = 0.f;
        #pragma unroll
        for (int p = 0; p < 8; ++p) acc += qred[p][t];
        q[t] = acc;
    }
    __syncthreads();
    {
        const int j = t & 127, cg = t >> 7;
        const float qj = q[j];
        for (int c0 = 0; c0 < 128; c0 += 8) {
            const int c = c0 + cg;
            float v = Wn[c * 384 + j] * qj;
            v += __shfl_down(v, 8, 16);
            v += __shfl_down(v, 4, 16);
            v += __shfl_down(v, 2, 16);
            v += __shfl_down(v, 1, 16);
            if ((j & 15) == 0) {
                const int h = j >> 4, s = c >> 2;
                qkf[h * 128 + (s ^ (s >> 2)) * 4 + (c & 3)] = v * 0.25f;
            }
        }
    }
    __syncthreads();

    const bool useB = (flagS != 0);

    if (t < 8) { mh[t] = -3e38f; lh[t] = 0.f; }
    float4 eacc[8];
    #pragma unroll
    for (int h = 0; h < 8; ++h) eacc[h] = make_float4(0.f, 0.f, 0.f, 0.f);
    const int c4 = t & 31, sl = t >> 5;
    const int rr = t >> 3, qq = t & 7;

    for (int tile = 0; tile < 8; ++tile) {
        const int r0 = tile * 128;
        {
            const int g = r0 + rr;
            float4 v[4];
            if (g < 1000) {
                #pragma unroll
                for (int i = 0; i < 4; ++i) v[i] = E4[g * 32 + qq * 4 + i];
            } else {
                #pragma unroll
                for (int i = 0; i < 4; ++i) v[i] = make_float4(0.f, 0.f, 0.f, 0.f);
            }
            float pch[8];
            #pragma unroll
            for (int h = 0; h < 8; ++h) pch[h] = 0.f;
            #pragma unroll
            for (int i = 0; i < 4; ++i) {
                const int grp = qq * 4 + i;
                Et[rr * 32 + (grp ^ (rr & 7))] = v[i];
                const int sg = grp ^ (grp >> 2);
                #pragma unroll
                for (int h = 0; h < 8; ++h) {
                    const float4 w = qk4[h * 32 + sg];
                    pch[h] += v[i].x * w.x + v[i].y * w.y + v[i].z * w.z + v[i].w * w.w;
                }
            }
            #pragma unroll
            for (int m = 1; m <= 4; m <<= 1) {
                #pragma unroll
                for (int h = 0; h < 8; ++h) pch[h] += __shfl_xor(pch[h], m, 64);
            }
            bool msk = (g >= 1000);
            if (!msk) msk = useB ? (maskB[b * 1000 + g] != 0)
                                 : (maskI[b * 1000 + g] != 0);
            ct[rr * 9 + qq] = msk ? NEG : pch[qq];
        }
        __syncthreads();
        if (t < 64) {
            const int h = t & 7, part = t >> 3;
            float mt = -3e38f;
            const int rb = part * 16;
            for (int r = 0; r < 16; ++r) mt = fmaxf(mt, ct[(rb + r) * 9 + h]);
            redh[part * 9 + h] = mt;
        }
        __syncthreads();
        if (t < 8) {
            float mt = redh[t];
            for (int p = 1; p < 8; ++p) mt = fmaxf(mt, redh[p * 9 + t]);
            const float mnew = fmaxf(mh[t], mt);
            al[t] = __expf(mh[t] - mnew);
            mh[t] = mnew;
        }
        __syncthreads();
        {
            const int row = t >> 3, h = t & 7;
            pt[row * 8 + h] = __expf(ct[row * 9 + h] - mh[h]);
        }
        __syncthreads();
        {
            #pragma unroll
            for (int h = 0; h < 8; ++h) {
                const float a = al[h];
                eacc[h].x *= a; eacc[h].y *= a; eacc[h].z *= a; eacc[h].w *= a;
            }
            #pragma unroll
            for (int j = 0; j < 4; ++j) {
                const int r = sl * 4 + j;
                const float4 ev = Et[r * 32 + (c4 ^ (r & 7))];
                const float4 p0 = pt4[r * 2];
                const float4 p1 = pt4[r * 2 + 1];
                eacc[0].x += p0.x * ev.x; eacc[0].y += p0.x * ev.y; eacc[0].z += p0.x * ev.z; eacc[0].w += p0.x * ev.w;
                eacc[1].x += p0.y * ev.x; eacc[1].y += p0.y * ev.y; eacc[1].z += p0.y * ev.z; eacc[1].w += p0.y * ev.w;
                eacc[2].x += p0.z * ev.x; eacc[2].y += p0.z * ev.y; eacc[2].z += p0.z * ev.z; eacc[2].w += p0.z * ev.w;
                eacc[3].x += p0.w * ev.x; eacc[3].y += p0.w * ev.y; eacc[3].z += p0.w * ev.z; eacc[3].w += p0.w * ev.w;
                eacc[4].x += p1.x * ev.x; eacc[4].y += p1.x * ev.y; eacc[4].z += p1.x * ev.z; eacc[4].w += p1.x * ev.w;
                eacc[5].x += p1.y * ev.x; eacc[5].y += p1.y * ev.y; eacc[5].z += p1.y * ev.z; eacc[5].w += p1.y * ev.w;
                eacc[6].x += p1.z * ev.x; eacc[6].y += p1.z * ev.y; eacc[6].z += p1.z * ev.z; eacc[6].w += p1.z * ev.w;
                eacc[7].x += p1.w * ev.x; eacc[7].y += p1.w * ev.y; eacc[7].z += p1.w * ev.z; eacc[7].w += p1.w * ev.w;
            }
        }
        if (t < 64) {
            const int h = t & 7, part = t >> 3;
            float s = 0.f;
            const int rb = part * 16;
            for (int r = 0; r < 16; ++r) s += pt[(rb + r) * 8 + h];
            redh[part * 9 + h] = s;
        }
        __syncthreads();
        if (t < 8) {
            float s = 0.f;
            for (int p = 0; p < 8; ++p) s += redh[p * 9 + t];
            lh[t] = lh[t] * al[t] + s;
        }
    }

    if (sl >= 16) {
        #pragma unroll
        for (int h = 0; h < 8; ++h) Et[(sl - 16) * 256 + h * 32 + c4] = eacc[h];
    }
    __syncthreads();
    if (sl < 16) {
        #pragma unroll
        for (int h = 0; h < 8; ++h) {
            const float4 o = Et[sl * 256 + h * 32 + c4];
            eacc[h].x += o.x; eacc[h].y += o.y; eacc[h].z += o.z; eacc[h].w += o.w;
            Et[sl * 256 + h * 32 + c4] = eacc[h];
        }
    }
    __syncthreads();
    if (t < 256) {
        const int h = t >> 5, cc = t & 31;
        float4 s = make_float4(0.f, 0.f, 0.f, 0.f);
        #pragma unroll
        for (int s2 = 0; s2 < 16; ++s2) {
            const float4 v = Et[s2 * 256 + h * 32 + cc];
            s.x += v.x; s.y += v.y; s.z += v.z; s.w += v.w;
        }
        const float invl = 1.0f / lh[h];
        EbarF4[h * 32 + cc] = make_float4(s.x * invl, s.y * invl, s.z * invl, s.w * invl);
    }
    __syncthreads();

    {
        const int part = t >> 7, d = t & 127, h = d >> 4;
        float acc = 0.f;
        const int c0 = part * 16;
        for (int c = c0; c < c0 + 16; ++c) acc += EbarF[h * 128 + c] * Wn[c * 384 + 128 + d];
        qred[part][d] = acc;
    }
    __syncthreads();
    if (t < 128) {
        float acc = 0.f;
        #pragma unroll
        for (int p = 0; p < 8; ++p) acc += qred[p][t];
        heads[t] = acc;
    }
    __syncthreads();
    {
        const int part = t >> 7, d = t & 127;
        float acc = 0.f;
        const int j0 = part * 16;
        for (int j = j0; j < j0 + 16; ++j) acc += heads[j] * Wo[j * 128 + d];
        qred[part][d] = acc;
    }
    __syncthreads();
    if (t < 128) {
        float acc = 0.f;
        #pragma unroll
        for (int p = 0; p < 8; ++p) acc += qred[p][t];
        gl[t] = acc;
    }
    __syncthreads();
    {
        const int part = t >> 7, c = t & 127;
        float acc = 0.f;
        const int d0 = part * 16;
        for (int d = d0; d < d0 + 16; ++d) acc += Wn[c * 384 + 256 + d] * gl[d];
        qred[part][c] = acc;
    }
    __syncthreads();
    if (t < 128) {
        float acc = 0.f;
        #pragma unroll
        for (int p = 0; p < 8; ++p) acc += qred[p][t];
        gp[t] = acc * 0.08838834764831845f;
    }
    __syncthreads();

    {
        const int row = t >> 3, sub = t & 7;
        for (int tile = 0; tile < 8; ++tile) {
            const int g = tile * 128 + row;
            float acc = 0.f;
            if (g < 1000) {
                #pragma unroll
                for (int i = 0; i < 4; ++i) {
                    const float4 v = E4[g * 32 + sub * 4 + i];
                    const float4 w = gp4[sub * 4 + i];
                    acc += v.x * w.x + v.y * w.y + v.z * w.z + v.w * w.w;
                }
            }
            ct[row * 9 + sub] = acc;
            __syncthreads();
            if (t < 128) {
                const int g2 = tile * 128 + t;
                if (g2 < 1000) {
                    float s = 0.f;
                    #pragma unroll
                    for (int k = 0; k < 8; ++k) s += ct[t * 9 + k];
                    float zz = 10.0f * tanhf(s);
                    const bool m = useB ? (maskB[b * 1000 + g2] != 0)
                                        : (maskI[b * 1000 + g2] != 0);
                    if (m) zz = NEG;
                    pt[g2] = zz;
                }
            }
            __syncthreads();
        }
    }
    float v = (t < 1000) ? pt[t] : -3e38f;
    #pragma unroll
    for (int off = 32; off > 0; off >>= 1) v = fmaxf(v, __shfl_down(v, off, 64));
    if ((t & 63) == 0) red[t >> 6] = v;
    __syncthreads();
    if (t == 0) {
        float m = red[0];
        for (int i = 1; i < 16; ++i) m = fmaxf(m, red[i]);
        stat[0] = m;
    }
    __syncthreads();
    float sv = (t < 1000) ? __expf(pt[t] - stat[0]) : 0.f;
    #pragma unroll
    for (int off = 32; off > 0; off >>= 1) sv += __shfl_down(sv, off, 64);
    if ((t & 63) == 0) red[t >> 6] = sv;
    __syncthreads();
    if (t == 0) {
        float s = 0.f;
        for (int i = 0; i < 16; ++i) s += red[i];
        stat[1] = stat[0] + __logf(s);
    }
    __syncthreads();
    if (t < 1000)
        out[(size_t)b * 1000 + t] = pt[t] - stat[1];
}

// ---------------------------------------------------------------------------
extern "C" void kernel_launch(void* const* d_in, const int* in_sizes, int n_in,
                              void* d_out, int out_size, void* d_ws, size_t ws_size,
                              hipStream_t stream) {
    const float* E  = (const float*)d_in[0];
    const float* Wn = (const float*)d_in[1];
    const float* Wf = (const float*)d_in[2];
    const float* Ws = (const float*)d_in[3];
    const float* Wo = (const float*)d_in[4];
    const int*   fi = (const int*)d_in[5];
    const int*   li = (const int*)d_in[6];
    const int*   maskI = (const int*)d_in[7];
    const unsigned char* maskB = (const unsigned char*)d_in[7];
    float* out = (float*)d_out;
    float* ws  = (float*)d_ws;

    // reset pair counters (first 256 ints of workspace)
    hipMemsetAsync(d_ws, 0, 256 * sizeof(int), stream);

    void* args[] = {(void*)&E, (void*)&Wn, (void*)&Wf, (void*)&Ws, (void*)&Wo,
                    (void*)&fi, (void*)&li, (void*)&maskI, (void*)&maskB,
                    (void*)&out, (void*)&ws};
    const hipError_t err = hipLaunchCooperativeKernel(
        (const void*)k_pair, dim3(512), dim3(1024), args, 0, stream);
    if (err != hipSuccess) {
        // Co-residency rejected (e.g. VGPR > 64 -> 1 block/CU). The pair
        // kernel would deadlock-prone under a normal launch, so run the
        // verified single-block-per-b kernel instead.
        k_fused1<<<dim3(256), dim3(1024), 0, stream>>>(
            E, Wn, Wf, Ws, Wo, fi, li, maskI, maskB, out);
    }
}

// Round 8
// 282.194 us; speedup vs baseline: 21263.6120x; 21263.6120x over previous
//
#include <hip/hip_runtime.h>

// Problem: B=256, N=1000, D=128, H=8, dk=16.
// R8 (resubmit after GPUAcquisitionTimeout): R7b's 6.0s = 3 x 2s spin timeouts
// -> pair blocks never co-resident. Root cause: plain __launch_bounds__(1024)
// -> VGPR>64 -> 1 block/CU -> the 512 cooperative blocks serialized (ROCm coop
// check didn't reject). Observed rule: __launch_bounds__(1024,N) caps VGPR at
// 256/N (R6: N=8 -> 32, spills).
// Fix: (1) __launch_bounds__(1024,4) -> cap 64 VGPR = exact 2-blocks/CU
// boundary, no spill expected (R0 fit heavier code in 64); (2) host-side
// occupancy gate: require >=2 blocks/CU else run verified fallback (visible
// diagnostic, not a timeout crawl); (3) timeout 2s -> ~20ms.
// R4/R5 "container failed twice" = the UNBOUNDED spin hanging, not infra.

#define NEG (-1e9f)

__device__ __forceinline__ float ld_agent(const float* p) {
    return __hip_atomic_load((float*)p, __ATOMIC_RELAXED, __HIP_MEMORY_SCOPE_AGENT);
}

__device__ __forceinline__ void pair_arrive_wait(int* c, int target) {
    __syncthreads();                      // all waves' global stores drained (vmcnt 0)
    if (threadIdx.x == 0) {
        // release RMW: wbL2 before the atomic -> our half's ws data at the
        // device coherence point before the counter bump becomes visible
        __hip_atomic_fetch_add(c, 1, __ATOMIC_RELEASE, __HIP_MEMORY_SCOPE_AGENT);
        const long long t0 = (long long)__builtin_amdgcn_s_memrealtime();
        while (__hip_atomic_load(c, __ATOMIC_RELAXED, __HIP_MEMORY_SCOPE_AGENT) < target) {
            __builtin_amdgcn_s_sleep(4);
            // ~100 MHz realtime clock: 2e6 ticks ~= 20 ms. Bail, don't hang.
            if ((long long)__builtin_amdgcn_s_memrealtime() - t0 > 2000000LL) break;
        }
    }
    __syncthreads();
    // NOTE: no threadfence. Partner data must be read with ld_agent() only.
}

__global__ __launch_bounds__(1024, 4) void k_pair(
    const float* __restrict__ E, const float* __restrict__ Wn,
    const float* __restrict__ Wf, const float* __restrict__ Ws,
    const float* __restrict__ Wo,
    const int* __restrict__ fi, const int* __restrict__ li,
    const int* __restrict__ maskI, const unsigned char* __restrict__ maskB,
    float* __restrict__ out, float* __restrict__ ws)
{
    const int bid  = blockIdx.x;
    const int b    = bid & 255;
    const int half = bid >> 8;
    const int blk  = b * 2 + half;
    const int i0   = b * 2, i1 = b * 2 + 1;
    const int t    = threadIdx.x;
    const int r0g  = half * 500;          // first global row of this half

    int*   cnt  = (int*)ws;               // [256]  (memset to 0 each launch)
    float* muP  = ws + 256;               // [512][128] partial sums
    float* wsU  = muP + 512 * 128;        // [512][8*128] unnormalized Ebar numerator
    float* wsML = wsU + (size_t)512 * 1024; // [512][16] = m[8], l[8]
    float* wsZ  = wsML + 512 * 16;        // [512][2]  = zmax, zsum

    __shared__ float4 Et4[2048];     // 32 KB: mean scratch / 64-row E tile / slice reduce
    __shared__ float4 qk4[256];      // qkp, float4-slot swizzle s^(s>>2)
    __shared__ float4 pt4[128];      // p [row][h] in phase C; z[] (500) in phase E
    __shared__ float4 EbarF4[256];
    __shared__ float4 mu4[32], e14[32], e24[32], gp4[32];
    __shared__ float q[128], heads[128], gl[128];
    __shared__ float qred[8][128];
    __shared__ float ct[128 * 9];    // compat [row][h] pad 9 (64 rows in C; 128 in E)
    __shared__ float redh[72];
    __shared__ float mh[8], lh[8], al[8];
    __shared__ float red[16];
    __shared__ float stat[2];
    __shared__ int flagS;

    float* const mu    = (float*)mu4;
    float* const e1    = (float*)e14;
    float* const e2    = (float*)e24;
    float* const gp    = (float*)gp4;
    float* const pt    = (float*)pt4;
    float* const EbarF = (float*)EbarF4;
    float* const qkf   = (float*)qk4;
    float* const Etf   = (float*)Et4;

    const float4* E4 = (const float4*)(E + (size_t)b * 128000);

    if (t == 0) flagS = 0;
    // mask-format probe: int32 upload => upper 3 bytes of every word zero.
    const uint4 dv = ((const uint4*)maskI)[t];           // first 16 KB
    const unsigned det = (dv.x | dv.y | dv.z | dv.w) & 0xFFFFFF00u;

    // ---- Phase A: partial graph mean over this half's 500 rows ----
    {
        const int cm = t & 31, sm = t >> 5;
        float4 acc = make_float4(0.f, 0.f, 0.f, 0.f);
        for (int r = sm; r < 500; r += 32) {
            const float4 v = E4[(r0g + r) * 32 + cm];
            acc.x += v.x; acc.y += v.y; acc.z += v.z; acc.w += v.w;
        }
        Et4[t] = acc;
    }
    if (t >= 512 && t < 544) {
        e14[t - 512] = E4[fi[b] * 32 + (t - 512)];
    } else if (t >= 544 && t < 576) {
        e24[t - 544] = E4[li[b] * 32 + (t - 544)];
    }
    __syncthreads();
    if (det) atomicOr(&flagS, 1);
    if (t < 32) {
        float4 acc = Et4[t];
        #pragma unroll
        for (int s = 1; s < 32; ++s) {
            const float4 v = Et4[s * 32 + t];
            acc.x += v.x; acc.y += v.y; acc.z += v.z; acc.w += v.w;
        }
        ((float4*)(muP + (size_t)blk * 128))[t] = acc;   // partial SUM (not mean)
    }
    pair_arrive_wait(&cnt[b], 2);
    if (t < 128) {
        const float p0 = ld_agent(&muP[(size_t)i0 * 128 + t]);
        const float p1 = ld_agent(&muP[(size_t)i1 * 128 + t]);
        mu[t] = (p0 + p1) * (1.0f / 1000.0f);
    }
    __syncthreads();

    // ---- Phase B: q = mu@Wf + e1@Ws[0:128] + e2@Ws[128:256], 8-way k-split ----
    {
        const int part = t >> 7, d = t & 127;
        float acc = 0.f;
        const int k0 = part * 48;
        for (int k = k0; k < k0 + 48; ++k) {
            const float s = (k < 128) ? mu[k] : (k < 256 ? e1[k - 128] : e2[k - 256]);
            const float w = (k < 128) ? Wf[k * 128 + d] : Ws[(k - 128) * 128 + d];
            acc += s * w;
        }
        qred[part][d] = acc;
    }
    __syncthreads();
    if (t < 128) {
        float acc = 0.f;
        #pragma unroll
        for (int p = 0; p < 8; ++p) acc += qred[p][t];
        q[t] = acc;
    }
    __syncthreads();
    // qkp[h][c] -> qk4 (LDS only)
    {
        const int j = t & 127, cg = t >> 7;
        const float qj = q[j];
        for (int c0 = 0; c0 < 128; c0 += 8) {
            const int c = c0 + cg;
            float v = Wn[c * 384 + j] * qj;
            v += __shfl_down(v, 8, 16);
            v += __shfl_down(v, 4, 16);
            v += __shfl_down(v, 2, 16);
            v += __shfl_down(v, 1, 16);
            if ((j & 15) == 0) {
                const int h = j >> 4, s = c >> 2;
                qkf[h * 128 + (s ^ (s >> 2)) * 4 + (c & 3)] = v * 0.25f;
            }
        }
    }
    __syncthreads();

    const bool useB = (flagS != 0);

    // ---- Phase C: online-softmax glimpse attention, 8 tiles x 64 rows ----
    if (t < 8) { mh[t] = -3e38f; lh[t] = 0.f; }
    float eacc[8];
    #pragma unroll
    for (int h = 0; h < 8; ++h) eacc[h] = 0.f;
    const int rr = t >> 4, qq = t & 15;    // stage: 64 rows x 16 lanes
    const int esl = t >> 7, ec = t & 127;  // Ebar: 8 slices x 128 cols
    const int g1 = qq, g2 = qq + 16;
    const int sg1 = g1 ^ (g1 >> 2), sg2 = g2 ^ (g2 >> 2);

    for (int tile = 0; tile < 8; ++tile) {
        const int lr = tile * 64 + rr;
        const bool valid = (lr < 500);
        {
            float4 v0 = make_float4(0.f, 0.f, 0.f, 0.f), v1 = v0;
            if (valid) {
                v0 = E4[(r0g + lr) * 32 + g1];
                v1 = E4[(r0g + lr) * 32 + g2];
            }
            bool msk = !valid;
            if (valid && qq < 8)
                msk = useB ? (maskB[b * 1000 + r0g + lr] != 0)
                           : (maskI[b * 1000 + r0g + lr] != 0);
            Et4[rr * 32 + g1] = v0;        // linear row-major tile
            Et4[rr * 32 + g2] = v1;
            float pch[8];
            #pragma unroll
            for (int h = 0; h < 8; ++h) {
                const float4 w0 = qk4[h * 32 + sg1];
                const float4 w1 = qk4[h * 32 + sg2];
                pch[h] = v0.x * w0.x + v0.y * w0.y + v0.z * w0.z + v0.w * w0.w
                       + v1.x * w1.x + v1.y * w1.y + v1.z * w1.z + v1.w * w1.w;
            }
            #pragma unroll
            for (int m = 1; m <= 8; m <<= 1) {
                #pragma unroll
                for (int h = 0; h < 8; ++h) pch[h] += __shfl_xor(pch[h], m, 16);
            }
            if (qq < 8) ct[rr * 9 + qq] = msk ? NEG : pch[qq];
        }
        __syncthreads();
        if (t < 64) {
            const int h = t & 7, part = t >> 3;
            float mt = -3e38f;
            const int rb = part * 8;
            #pragma unroll
            for (int r = 0; r < 8; ++r) mt = fmaxf(mt, ct[(rb + r) * 9 + h]);
            redh[part * 9 + h] = mt;
        }
        __syncthreads();
        if (t < 8) {
            float mt = redh[t];
            #pragma unroll
            for (int p = 1; p < 8; ++p) mt = fmaxf(mt, redh[p * 9 + t]);
            const float mnew = fmaxf(mh[t], mt);
            al[t] = __expf(mh[t] - mnew);
            mh[t] = mnew;
        }
        __syncthreads();
        if (t < 512) {
            const int row = t >> 3, h = t & 7;
            pt[row * 8 + h] = __expf(ct[row * 9 + h] - mh[h]);
        }
        __syncthreads();
        {
            #pragma unroll
            for (int h = 0; h < 8; ++h) eacc[h] *= al[h];
            #pragma unroll
            for (int j = 0; j < 8; ++j) {
                const int r = esl * 8 + j;
                const float ev = Etf[r * 128 + ec];    // stride-1 across lanes: 2-way, free
                const float4 p0 = pt4[r * 2];          // broadcast
                const float4 p1 = pt4[r * 2 + 1];
                eacc[0] += p0.x * ev; eacc[1] += p0.y * ev;
                eacc[2] += p0.z * ev; eacc[3] += p0.w * ev;
                eacc[4] += p1.x * ev; eacc[5] += p1.y * ev;
                eacc[6] += p1.z * ev; eacc[7] += p1.w * ev;
            }
        }
        if (t < 64) {
            const int h = t & 7, part = t >> 3;
            float s = 0.f;
            const int rb = part * 8;
            #pragma unroll
            for (int r = 0; r < 8; ++r) s += pt[(rb + r) * 8 + h];
            redh[part * 9 + h] = s;
        }
        __syncthreads();
        // post-barrier lh update: redh/al not overwritten until next tile's
        // writers pass their next barrier — safe.
        if (t < 8) {
            float s = 0.f;
            #pragma unroll
            for (int p = 0; p < 8; ++p) s += redh[p * 9 + t];
            lh[t] = lh[t] * al[t] + s;
        }
    }

    // ---- slice reduce (8 slices fit Et in one go), publish {U,m,l} ----
    #pragma unroll
    for (int h = 0; h < 8; ++h) Etf[esl * 1024 + h * 128 + ec] = eacc[h];
    __syncthreads();
    {
        float s = 0.f;
        #pragma unroll
        for (int s2 = 0; s2 < 8; ++s2) s += Etf[s2 * 1024 + t];
        wsU[(size_t)blk * 1024 + t] = s;           // unnormalized, local max
    }
    if (t < 8) wsML[blk * 16 + t] = mh[t];
    else if (t < 16) wsML[blk * 16 + t] = lh[t - 8];
    pair_arrive_wait(&cnt[b], 4);
    // combine halves: Ebar = (U0*w0 + U1*w1) / (l0*w0 + l1*w1), w_i = exp(m_i - M)
    if (t < 8) {
        const float m0 = ld_agent(&wsML[i0 * 16 + t]);
        const float m1 = ld_agent(&wsML[i1 * 16 + t]);
        const float l0 = ld_agent(&wsML[i0 * 16 + 8 + t]);
        const float l1 = ld_agent(&wsML[i1 * 16 + 8 + t]);
        const float M = fmaxf(m0, m1);
        const float w0 = __expf(m0 - M), w1 = __expf(m1 - M);
        const float L = l0 * w0 + l1 * w1;
        redh[t] = w0 / L;
        redh[8 + t] = w1 / L;
    }
    __syncthreads();
    {
        const int h = t >> 7;
        const float u0 = ld_agent(&wsU[(size_t)i0 * 1024 + t]);
        const float u1 = ld_agent(&wsU[(size_t)i1 * 1024 + t]);
        EbarF[t] = u0 * redh[h] + u1 * redh[8 + h];
    }
    __syncthreads();

    // ---- Phase D: heads -> glimpse -> gp, 8-way k-split each (duplicated) ----
    {
        const int part = t >> 7, d = t & 127, h = d >> 4;
        float acc = 0.f;
        const int c0 = part * 16;
        for (int c = c0; c < c0 + 16; ++c) acc += EbarF[h * 128 + c] * Wn[c * 384 + 128 + d];
        qred[part][d] = acc;
    }
    __syncthreads();
    if (t < 128) {
        float acc = 0.f;
        #pragma unroll
        for (int p = 0; p < 8; ++p) acc += qred[p][t];
        heads[t] = acc;
    }
    __syncthreads();
    {
        const int part = t >> 7, d = t & 127;
        float acc = 0.f;
        const int j0 = part * 16;
        for (int j = j0; j < j0 + 16; ++j) acc += heads[j] * Wo[j * 128 + d];
        qred[part][d] = acc;
    }
    __syncthreads();
    if (t < 128) {
        float acc = 0.f;
        #pragma unroll
        for (int p = 0; p < 8; ++p) acc += qred[p][t];
        gl[t] = acc;
    }
    __syncthreads();
    {
        const int part = t >> 7, c = t & 127;
        float acc = 0.f;
        const int d0 = part * 16;
        for (int d = d0; d < d0 + 16; ++d) acc += Wn[c * 384 + 256 + d] * gl[d];
        qred[part][c] = acc;
    }
    __syncthreads();
    if (t < 128) {
        float acc = 0.f;
        #pragma unroll
        for (int p = 0; p < 8; ++p) acc += qred[p][t];
        gp[t] = acc * 0.08838834764831845f;   // 1/sqrt(128)
    }
    __syncthreads();

    // ---- Phase E: logits for this half's 500 rows + split log_softmax ----
    {
        const int row = t >> 3, sub = t & 7;
        for (int tile = 0; tile < 4; ++tile) {
            const int lr = tile * 128 + row;
            float acc = 0.f;
            if (lr < 500) {
                const int g = r0g + lr;
                #pragma unroll
                for (int i = 0; i < 4; ++i) {
                    const float4 v = E4[g * 32 + sub * 4 + i];
                    const float4 w = gp4[sub * 4 + i];
                    acc += v.x * w.x + v.y * w.y + v.z * w.z + v.w * w.w;
                }
            }
            ct[row * 9 + sub] = acc;
            __syncthreads();
            if (t < 128) {
                const int lr2 = tile * 128 + t;
                if (lr2 < 500) {
                    float s = 0.f;
                    #pragma unroll
                    for (int k = 0; k < 8; ++k) s += ct[t * 9 + k];
                    float zz = 10.0f * tanhf(s);
                    const int g2 = r0g + lr2;
                    const bool m = useB ? (maskB[b * 1000 + g2] != 0)
                                        : (maskI[b * 1000 + g2] != 0);
                    if (m) zz = NEG;
                    pt[lr2] = zz;
                }
            }
            __syncthreads();
        }
    }
    // local max/sum over 500, then pair-combine LSE
    {
        float v = (t < 500) ? pt[t] : -3e38f;
        if (t < 512) {
            #pragma unroll
            for (int off = 32; off > 0; off >>= 1) v = fmaxf(v, __shfl_down(v, off, 64));
            if ((t & 63) == 0) red[t >> 6] = v;
        }
    }
    __syncthreads();
    if (t == 0) {
        float m = red[0];
        for (int i = 1; i < 8; ++i) m = fmaxf(m, red[i]);
        stat[0] = m;
    }
    __syncthreads();
    {
        float sv = (t < 500) ? __expf(pt[t] - stat[0]) : 0.f;
        if (t < 512) {
            #pragma unroll
            for (int off = 32; off > 0; off >>= 1) sv += __shfl_down(sv, off, 64);
            if ((t & 63) == 0) red[t >> 6] = sv;
        }
    }
    __syncthreads();
    if (t == 0) {
        float s = 0.f;
        for (int i = 0; i < 8; ++i) s += red[i];
        wsZ[blk * 2] = stat[0];
        wsZ[blk * 2 + 1] = s;
    }
    pair_arrive_wait(&cnt[b], 6);
    if (t == 0) {
        const float m0 = ld_agent(&wsZ[i0 * 2]), s0 = ld_agent(&wsZ[i0 * 2 + 1]);
        const float m1 = ld_agent(&wsZ[i1 * 2]), s1 = ld_agent(&wsZ[i1 * 2 + 1]);
        const float M = fmaxf(m0, m1);
        const float S = s0 * __expf(m0 - M) + s1 * __expf(m1 - M);
        stat[1] = M + __logf(S);
    }
    __syncthreads();
    if (t < 500)
        out[(size_t)b * 1000 + r0g + t] = pt[t] - stat[1];
}

// ======================= fallback: verified R0 single-block kernel ==========
__global__ __launch_bounds__(1024) void k_fused1(
    const float* __restrict__ E, const float* __restrict__ Wn,
    const float* __restrict__ Wf, const float* __restrict__ Ws,
    const float* __restrict__ Wo,
    const int* __restrict__ fi, const int* __restrict__ li,
    const int* __restrict__ maskI, const unsigned char* __restrict__ maskB,
    float* __restrict__ out)
{
    const int b = blockIdx.x;
    const int t = threadIdx.x;

    __shared__ float4 Et[4096];
    __shared__ float4 qk4[256];
    __shared__ float4 pt4[256];
    __shared__ float4 EbarF4[256];
    __shared__ float4 mu4[32], e14[32], e24[32], gp4[32];
    __shared__ float q[128], heads[128], gl[128];
    __shared__ float qred[8][128];
    __shared__ float ct[128 * 9];
    __shared__ float redh[72];
    __shared__ float mh[8], lh[8], al[8];
    __shared__ float red[16];
    __shared__ float stat[2];
    __shared__ int flagS;

    float* const mu = (float*)mu4;
    float* const e1 = (float*)e14;
    float* const e2 = (float*)e24;
    float* const gp = (float*)gp4;
    float* const pt = (float*)pt4;
    float* const EbarF = (float*)EbarF4;
    float* const qkf = (float*)qk4;

    const float4* E4 = (const float4*)(E + (size_t)b * 128000);

    if (t == 0) flagS = 0;
    const uint4 dv = ((const uint4*)maskI)[t];
    const unsigned det = (dv.x | dv.y | dv.z | dv.w) & 0xFFFFFF00u;

    {
        const int cm = t & 31, sm = t >> 5;
        float4 acc = make_float4(0.f, 0.f, 0.f, 0.f);
        for (int r = sm; r < 1000; r += 32) {
            const float4 v = E4[r * 32 + cm];
            acc.x += v.x; acc.y += v.y; acc.z += v.z; acc.w += v.w;
        }
        Et[t] = acc;
    }
    if (t >= 512 && t < 544) {
        e14[t - 512] = E4[fi[b] * 32 + (t - 512)];
    } else if (t >= 544 && t < 576) {
        e24[t - 544] = E4[li[b] * 32 + (t - 544)];
    }
    __syncthreads();
    if (det) atomicOr(&flagS, 1);
    if (t < 32) {
        float4 acc = Et[t];
        #pragma unroll
        for (int s = 1; s < 32; ++s) {
            const float4 v = Et[s * 32 + t];
            acc.x += v.x; acc.y += v.y; acc.z += v.z; acc.w += v.w;
        }
        const float inv = 1.0f / 1000.0f;
        mu4[t] = make_float4(acc.x * inv, acc.y * inv, acc.z * inv, acc.w * inv);
    }
    __syncthreads();

    {
        const int part = t >> 7, d = t & 127;
        float acc = 0.f;
        const int k0 = part * 48;
        for (int k = k0; k < k0 + 48; ++k) {
            const float s = (k < 128) ? mu[k] : (k < 256 ? e1[k - 128] : e2[k - 256]);
            const float w = (k < 128) ? Wf[k * 128 + d] : Ws[(k - 128) * 128 + d];
            acc += s * w;
        }
        qred[part][d] = acc;
    }
    __syncthreads();
    if (t < 128) {
        float acc = 0.f;
        #pragma unroll
        for (int p = 0; p < 8; ++p) acc += qred[p][t];
        q[t] = acc;
    }
    __syncthreads();
    {
        const int j = t & 127, cg = t >> 7;
        const float qj = q[j];
        for (int c0 = 0; c0 < 128; c0 += 8) {
            const int c = c0 + cg;
            float v = Wn[c * 384 + j] * qj;
            v += __shfl_down(v, 8, 16);
            v += __shfl_down(v, 4, 16);
            v += __shfl_down(v, 2, 16);
            v += __shfl_down(v, 1, 16);
            if ((j & 15) == 0) {
                const int h = j >> 4, s = c >> 2;
                qkf[h * 128 + (s ^ (s >> 2)) * 4 + (c & 3)] = v * 0.25f;
            }
        }
    }
    __syncthreads();

    const bool useB = (flagS != 0);

    if (t < 8) { mh[t] = -3e38f; lh[t] = 0.f; }
    float4 eacc[8];
    #pragma unroll
    for (int h = 0; h < 8; ++h) eacc[h] = make_float4(0.f, 0.f, 0.f, 0.f);
    const int c4 = t & 31, sl = t >> 5;
    const int rr = t >> 3, qq = t & 7;

    for (int tile = 0; tile < 8; ++tile) {
        const int r0 = tile * 128;
        {
            const int g = r0 + rr;
            float4 v[4];
            if (g < 1000) {
                #pragma unroll
                for (int i = 0; i < 4; ++i) v[i] = E4[g * 32 + qq * 4 + i];
            } else {
                #pragma unroll
                for (int i = 0; i < 4; ++i) v[i] = make_float4(0.f, 0.f, 0.f, 0.f);
            }
            float pch[8];
            #pragma unroll
            for (int h = 0; h < 8; ++h) pch[h] = 0.f;
            #pragma unroll
            for (int i = 0; i < 4; ++i) {
                const int grp = qq * 4 + i;
                Et[rr * 32 + (grp ^ (rr & 7))] = v[i];
                const int sg = grp ^ (grp >> 2);
                #pragma unroll
                for (int h = 0; h < 8; ++h) {
                    const float4 w = qk4[h * 32 + sg];
                    pch[h] += v[i].x * w.x + v[i].y * w.y + v[i].z * w.z + v[i].w * w.w;
                }
            }
            #pragma unroll
            for (int m = 1; m <= 4; m <<= 1) {
                #pragma unroll
                for (int h = 0; h < 8; ++h) pch[h] += __shfl_xor(pch[h], m, 64);
            }
            bool msk = (g >= 1000);
            if (!msk) msk = useB ? (maskB[b * 1000 + g] != 0)
                                 : (maskI[b * 1000 + g] != 0);
            ct[rr * 9 + qq] = msk ? NEG : pch[qq];
        }
        __syncthreads();
        if (t < 64) {
            const int h = t & 7, part = t >> 3;
            float mt = -3e38f;
            const int rb = part * 16;
            for (int r = 0; r < 16; ++r) mt = fmaxf(mt, ct[(rb + r) * 9 + h]);
            redh[part * 9 + h] = mt;
        }
        __syncthreads();
        if (t < 8) {
            float mt = redh[t];
            for (int p = 1; p < 8; ++p) mt = fmaxf(mt, redh[p * 9 + t]);
            const float mnew = fmaxf(mh[t], mt);
            al[t] = __expf(mh[t] - mnew);
            mh[t] = mnew;
        }
        __syncthreads();
        {
            const int row = t >> 3, h = t & 7;
            pt[row * 8 + h] = __expf(ct[row * 9 + h] - mh[h]);
        }
        __syncthreads();
        {
            #pragma unroll
            for (int h = 0; h < 8; ++h) {
                const float a = al[h];
                eacc[h].x *= a; eacc[h].y *= a; eacc[h].z *= a; eacc[h].w *= a;
            }
            #pragma unroll
            for (int j = 0; j < 4; ++j) {
                const int r = sl * 4 + j;
                const float4 ev = Et[r * 32 + (c4 ^ (r & 7))];
                const float4 p0 = pt4[r * 2];
                const float4 p1 = pt4[r * 2 + 1];
                eacc[0].x += p0.x * ev.x; eacc[0].y += p0.x * ev.y; eacc[0].z += p0.x * ev.z; eacc[0].w += p0.x * ev.w;
                eacc[1].x += p0.y * ev.x; eacc[1].y += p0.y * ev.y; eacc[1].z += p0.y * ev.z; eacc[1].w += p0.y * ev.w;
                eacc[2].x += p0.z * ev.x; eacc[2].y += p0.z * ev.y; eacc[2].z += p0.z * ev.z; eacc[2].w += p0.z * ev.w;
                eacc[3].x += p0.w * ev.x; eacc[3].y += p0.w * ev.y; eacc[3].z += p0.w * ev.z; eacc[3].w += p0.w * ev.w;
                eacc[4].x += p1.x * ev.x; eacc[4].y += p1.x * ev.y; eacc[4].z += p1.x * ev.z; eacc[4].w += p1.x * ev.w;
                eacc[5].x += p1.y * ev.x; eacc[5].y += p1.y * ev.y; eacc[5].z += p1.y * ev.z; eacc[5].w += p1.y * ev.w;
                eacc[6].x += p1.z * ev.x; eacc[6].y += p1.z * ev.y; eacc[6].z += p1.z * ev.z; eacc[6].w += p1.z * ev.w;
                eacc[7].x += p1.w * ev.x; eacc[7].y += p1.w * ev.y; eacc[7].z += p1.w * ev.z; eacc[7].w += p1.w * ev.w;
            }
        }
        if (t < 64) {
            const int h = t & 7, part = t >> 3;
            float s = 0.f;
            const int rb = part * 16;
            for (int r = 0; r < 16; ++r) s += pt[(rb + r) * 8 + h];
            redh[part * 9 + h] = s;
        }
        __syncthreads();
        if (t < 8) {
            float s = 0.f;
            for (int p = 0; p < 8; ++p) s += redh[p * 9 + t];
            lh[t] = lh[t] * al[t] + s;
        }
    }

    if (sl >= 16) {
        #pragma unroll
        for (int h = 0; h < 8; ++h) Et[(sl - 16) * 256 + h * 32 + c4] = eacc[h];
    }
    __syncthreads();
    if (sl < 16) {
        #pragma unroll
        for (int h = 0; h < 8; ++h) {
            const float4 o = Et[sl * 256 + h * 32 + c4];
            eacc[h].x += o.x; eacc[h].y += o.y; eacc[h].z += o.z; eacc[h].w += o.w;
            Et[sl * 256 + h * 32 + c4] = eacc[h];
        }
    }
    __syncthreads();
    if (t < 256) {
        const int h = t >> 5, cc = t & 31;
        float4 s = make_float4(0.f, 0.f, 0.f, 0.f);
        #pragma unroll
        for (int s2 = 0; s2 < 16; ++s2) {
            const float4 v = Et[s2 * 256 + h * 32 + cc];
            s.x += v.x; s.y += v.y; s.z += v.z; s.w += v.w;
        }
        const float invl = 1.0f / lh[h];
        EbarF4[h * 32 + cc] = make_float4(s.x * invl, s.y * invl, s.z * invl, s.w * invl);
    }
    __syncthreads();

    {
        const int part = t >> 7, d = t & 127, h = d >> 4;
        float acc = 0.f;
        const int c0 = part * 16;
        for (int c = c0; c < c0 + 16; ++c) acc += EbarF[h * 128 + c] * Wn[c * 384 + 128 + d];
        qred[part][d] = acc;
    }
    __syncthreads();
    if (t < 128) {
        float acc = 0.f;
        #pragma unroll
        for (int p = 0; p < 8; ++p) acc += qred[p][t];
        heads[t] = acc;
    }
    __syncthreads();
    {
        const int part = t >> 7, d = t & 127;
        float acc = 0.f;
        const int j0 = part * 16;
        for (int j = j0; j < j0 + 16; ++j) acc += heads[j] * Wo[j * 128 + d];
        qred[part][d] = acc;
    }
    __syncthreads();
    if (t < 128) {
        float acc = 0.f;
        #pragma unroll
        for (int p = 0; p < 8; ++p) acc += qred[p][t];
        gl[t] = acc;
    }
    __syncthreads();
    {
        const int part = t >> 7, c = t & 127;
        float acc = 0.f;
        const int d0 = part * 16;
        for (int d = d0; d < d0 + 16; ++d) acc += Wn[c * 384 + 256 + d] * gl[d];
        qred[part][c] = acc;
    }
    __syncthreads();
    if (t < 128) {
        float acc = 0.f;
        #pragma unroll
        for (int p = 0; p < 8; ++p) acc += qred[p][t];
        gp[t] = acc * 0.08838834764831845f;
    }
    __syncthreads();

    {
        const int row = t >> 3, sub = t & 7;
        for (int tile = 0; tile < 8; ++tile) {
            const int g = tile * 128 + row;
            float acc = 0.f;
            if (g < 1000) {
                #pragma unroll
                for (int i = 0; i < 4; ++i) {
                    const float4 v = E4[g * 32 + sub * 4 + i];
                    const float4 w = gp4[sub * 4 + i];
                    acc += v.x * w.x + v.y * w.y + v.z * w.z + v.w * w.w;
                }
            }
            ct[row * 9 + sub] = acc;
            __syncthreads();
            if (t < 128) {
                const int g2 = tile * 128 + t;
                if (g2 < 1000) {
                    float s = 0.f;
                    #pragma unroll
                    for (int k = 0; k < 8; ++k) s += ct[t * 9 + k];
                    float zz = 10.0f * tanhf(s);
                    const bool m = useB ? (maskB[b * 1000 + g2] != 0)
                                        : (maskI[b * 1000 + g2] != 0);
                    if (m) zz = NEG;
                    pt[g2] = zz;
                }
            }
            __syncthreads();
        }
    }
    float v = (t < 1000) ? pt[t] : -3e38f;
    #pragma unroll
    for (int off = 32; off > 0; off >>= 1) v = fmaxf(v, __shfl_down(v, off, 64));
    if ((t & 63) == 0) red[t >> 6] = v;
    __syncthreads();
    if (t == 0) {
        float m = red[0];
        for (int i = 1; i < 16; ++i) m = fmaxf(m, red[i]);
        stat[0] = m;
    }
    __syncthreads();
    float sv = (t < 1000) ? __expf(pt[t] - stat[0]) : 0.f;
    #pragma unroll
    for (int off = 32; off > 0; off >>= 1) sv += __shfl_down(sv, off, 64);
    if ((t & 63) == 0) red[t >> 6] = sv;
    __syncthreads();
    if (t == 0) {
        float s = 0.f;
        for (int i = 0; i < 16; ++i) s += red[i];
        stat[1] = stat[0] + __logf(s);
    }
    __syncthreads();
    if (t < 1000)
        out[(size_t)b * 1000 + t] = pt[t] - stat[1];
}

// ---------------------------------------------------------------------------
extern "C" void kernel_launch(void* const* d_in, const int* in_sizes, int n_in,
                              void* d_out, int out_size, void* d_ws, size_t ws_size,
                              hipStream_t stream) {
    const float* E  = (const float*)d_in[0];
    const float* Wn = (const float*)d_in[1];
    const float* Wf = (const float*)d_in[2];
    const float* Ws = (const float*)d_in[3];
    const float* Wo = (const float*)d_in[4];
    const int*   fi = (const int*)d_in[5];
    const int*   li = (const int*)d_in[6];
    const int*   maskI = (const int*)d_in[7];
    const unsigned char* maskB = (const unsigned char*)d_in[7];
    float* out = (float*)d_out;
    float* ws  = (float*)d_ws;

    // Occupancy gate: pair kernel REQUIRES 2 blocks/CU co-residency. Host-side
    // query (no stream ops -> graph-capture safe), cached across launches.
    static int blocksPerCU = -1;
    if (blocksPerCU < 0) {
        int nb = 0;
        if (hipOccupancyMaxActiveBlocksPerMultiprocessor(&nb, k_pair, 1024, 0)
            != hipSuccess) nb = 0;
        blocksPerCU = nb;
    }

    if (blocksPerCU >= 2) {
        // reset pair counters (first 256 ints of workspace)
        hipMemsetAsync(d_ws, 0, 256 * sizeof(int), stream);
        void* args[] = {(void*)&E, (void*)&Wn, (void*)&Wf, (void*)&Ws, (void*)&Wo,
                        (void*)&fi, (void*)&li, (void*)&maskI, (void*)&maskB,
                        (void*)&out, (void*)&ws};
        const hipError_t err = hipLaunchCooperativeKernel(
            (const void*)k_pair, dim3(512), dim3(1024), args, 0, stream);
        if (err == hipSuccess) return;
    }
    // Co-residency unavailable (VGPR>64 or coop rejected): verified fallback.
    k_fused1<<<dim3(256), dim3(1024), 0, stream>>>(
        E, Wn, Wf, Ws, Wo, fi, li, maskI, maskB, out);
}